// Round 1
// baseline (93.139 us; speedup 1.0000x reference)
//
#include <hip/hip_runtime.h>

namespace {

constexpr int BATCH  = 4;
constexpr int SEQ    = 4096;
constexpr int IN_DIM = 64;
constexpr int DM     = 256;
constexpr float RES_SCALE = 0.1f;

// ---------------------------------------------------------------------------
// Kernel 1: per (batch, chunk) partial X = x_chunkĀ· x_chunk  (64x64) and
// partial column-sum c (64). No atomics -> bitwise deterministic.
// ---------------------------------------------------------------------------
__global__ __launch_bounds__(256)
void k_xtx(const float* __restrict__ x, float* __restrict__ Xp,
           float* __restrict__ cp, int nch) {
  const int blk = blockIdx.x;          // = b*nch + ch
  const int b   = blk / nch;
  const int ch  = blk - b * nch;
  const int chrows = SEQ / nch;
  const int t  = threadIdx.x;
  const int tr = t >> 4;               // 0..15
  const int tc = t & 15;               // 0..15

  __shared__ __align__(16) float xs[16][64];   // 16 staged rows
  __shared__ __align__(16) float cs[16][64];   // colsum partials

  const float* xb = x + ((size_t)b * SEQ + (size_t)ch * chrows) * IN_DIM;

  float acc[4][4];
#pragma unroll
  for (int i = 0; i < 4; ++i)
#pragma unroll
    for (int j = 0; j < 4; ++j) acc[i][j] = 0.f;
  float4 csum = make_float4(0.f, 0.f, 0.f, 0.f);

  const int nstage = chrows / 16;
  for (int st = 0; st < nstage; ++st) {
    // thread t loads row (st*16 + tr), cols tc*4..+3 : fully coalesced
    const float4 v = *reinterpret_cast<const float4*>(
        xb + (size_t)(st * 16 + tr) * IN_DIM + tc * 4);
    __syncthreads();  // protect xs from previous stage's readers
    *reinterpret_cast<float4*>(&xs[tr][tc * 4]) = v;
    csum.x += v.x; csum.y += v.y; csum.z += v.z; csum.w += v.w;
    __syncthreads();
#pragma unroll
    for (int s = 0; s < 16; ++s) {
      const float4 a  = *reinterpret_cast<const float4*>(&xs[s][tr * 4]);
      const float4 bb = *reinterpret_cast<const float4*>(&xs[s][tc * 4]);
      acc[0][0] += a.x * bb.x; acc[0][1] += a.x * bb.y;
      acc[0][2] += a.x * bb.z; acc[0][3] += a.x * bb.w;
      acc[1][0] += a.y * bb.x; acc[1][1] += a.y * bb.y;
      acc[1][2] += a.y * bb.z; acc[1][3] += a.y * bb.w;
      acc[2][0] += a.z * bb.x; acc[2][1] += a.z * bb.y;
      acc[2][2] += a.z * bb.z; acc[2][3] += a.z * bb.w;
      acc[3][0] += a.w * bb.x; acc[3][1] += a.w * bb.y;
      acc[3][2] += a.w * bb.z; acc[3][3] += a.w * bb.w;
    }
  }

  float* Xpb = Xp + (size_t)blk * (64 * 64);
#pragma unroll
  for (int i = 0; i < 4; ++i) {
    const float4 st4 = make_float4(acc[i][0], acc[i][1], acc[i][2], acc[i][3]);
    *reinterpret_cast<float4*>(Xpb + (size_t)(tr * 4 + i) * 64 + tc * 4) = st4;
  }
  *reinterpret_cast<float4*>(&cs[tr][tc * 4]) = csum;
  __syncthreads();
  if (t < 64) {
    float s = 0.f;
#pragma unroll
    for (int g = 0; g < 16; ++g) s += cs[g][t];
    cp[(size_t)blk * 64 + t] = s;
  }
}

// ---------------------------------------------------------------------------
// Chain kernel helpers (all called uniformly by 1024 threads)
// ---------------------------------------------------------------------------
__device__ __forceinline__ float wave_red(float s) {
  s += __shfl_down(s, 32); s += __shfl_down(s, 16); s += __shfl_down(s, 8);
  s += __shfl_down(s, 4);  s += __shfl_down(s, 2);  s += __shfl_down(s, 1);
  return s;
}

// dst[j] = sum_k v[k] * M[k*DM + j],  j<DM, K rows. M global, v/dst LDS.
template <int K>
__device__ __forceinline__ void mv_NT(const float* __restrict__ M,
                                      const float* v, float* dst,
                                      float (*pm)[DM], int t) {
  const int ks = t >> 6;      // 16 k-slices
  const int jg = t & 63;      // j = jg*4
  constexpr int kps = K >> 4; // per-slice depth
  float4 acc = make_float4(0.f, 0.f, 0.f, 0.f);
  const float* Mp = M + (size_t)ks * kps * DM + jg * 4;
#pragma unroll
  for (int i = 0; i < kps; ++i) {
    const float  vv = v[ks * kps + i];
    const float4 m  = *reinterpret_cast<const float4*>(Mp + (size_t)i * DM);
    acc.x += vv * m.x; acc.y += vv * m.y; acc.z += vv * m.z; acc.w += vv * m.w;
  }
  *reinterpret_cast<float4*>(&pm[ks][jg * 4]) = acc;
  __syncthreads();
  if (t < DM) {
    float s = 0.f;
#pragma unroll
    for (int g = 0; g < 16; ++g) s += pm[g][t];
    dst[t] = s;
  }
  __syncthreads();
}

// dst[r] = dot(v[0..DM-1], M[r*DM .. +DM-1]) for r < R. (i.e. dst = v @ M^T)
template <int R>
__device__ __forceinline__ void mv_TN(const float* __restrict__ M,
                                      const float* v, float* dst, int t) {
  const int w = t >> 6, l = t & 63;
  const float4 vv = *reinterpret_cast<const float4*>(v + l * 4);
  constexpr int rpw = R >> 4;  // rows per wave (16 waves)
#pragma unroll
  for (int i = 0; i < rpw; ++i) {
    const int r = w * rpw + i;
    const float4 m = *reinterpret_cast<const float4*>(M + (size_t)r * DM + l * 4);
    float s = m.x * vv.x + m.y * vv.y + m.z * vv.z + m.w * vv.w;
    s = wave_red(s);
    if (l == 0) dst[r] = s;
  }
  __syncthreads();
}

// dst = v @ G0, with G0 = Wemb^T X Wemb + u b^T + b u^T + SEQ b b^T (symmetric)
__device__ __forceinline__ void apply_G0(const float* v, float* dst,
    const float* __restrict__ Wemb, const float (*Xs)[64],
    const float* u, const float* bsv,
    float* r1, float* r2, float (*pm)[DM], float (*pms)[64],
    float* scal, int t) {
  // r1[k] = dot(v, Wemb[k,:])   (v @ Wemb^T)
  mv_TN<64>(Wemb, v, r1, t);
  // du = v.u ; db = v.b
  const int w = t >> 6, l = t & 63;
  if (w < 2) {
    const float* o = (w == 0) ? u : bsv;
    const float4 a  = *reinterpret_cast<const float4*>(v + l * 4);
    const float4 bb = *reinterpret_cast<const float4*>(o + l * 4);
    float s = a.x * bb.x + a.y * bb.y + a.z * bb.z + a.w * bb.w;
    s = wave_red(s);
    if (l == 0) scal[w] = s;
  }
  __syncthreads();
  // r2[j] = sum_k r1[k] * X[k][j]
  if (t < 256) {
    const int ks = t >> 6, j = t & 63;
    float s = 0.f;
#pragma unroll
    for (int i = 0; i < 16; ++i) s += r1[ks * 16 + i] * Xs[ks * 16 + i][j];
    pms[ks][j] = s;
  }
  __syncthreads();
  if (t < 64) r2[t] = pms[0][t] + pms[1][t] + pms[2][t] + pms[3][t];
  __syncthreads();
  // dst = r2 @ Wemb + du*b + db*u + SEQ*db*b
  mv_NT<64>(Wemb, r2, dst, pm, t);
  if (t < DM)
    dst[t] += scal[0] * bsv[t] + scal[1] * u[t] + (float)SEQ * scal[1] * bsv[t];
  __syncthreads();
}

// ---------------------------------------------------------------------------
// Kernel 2: one block per batch. Reduce partials, then the vector chain:
//   s2 = s0 A0 A1,  A_i = I + a Wq_i Wk_i^T G_i Wv_i,  G1 = A0^T G0 A0
// applied purely as vec-mat products (G0 and A never materialized).
// ---------------------------------------------------------------------------
__global__ __launch_bounds__(1024)
void k_chain(const float* __restrict__ Xp, const float* __restrict__ cp,
             const float* __restrict__ Wemb, const float* __restrict__ bemb,
             const float* __restrict__ Wq, const float* __restrict__ Wk,
             const float* __restrict__ Wv, const float* __restrict__ Wout,
             const float* __restrict__ bout, float* __restrict__ out, int nch) {
  const int b = blockIdx.x;
  const int t = threadIdx.x;

  __shared__ __align__(16) float Xs[64][64];
  __shared__ __align__(16) float pm[16][DM];
  __shared__ __align__(16) float pms[4][64];
  __shared__ __align__(16) float vec[6][DM];  // 0:u 1:s0 2:s1 3:A 4:B 5:D
  __shared__ __align__(16) float bs[DM];
  __shared__ __align__(16) float cvec[64];
  __shared__ __align__(16) float r1[64];
  __shared__ __align__(16) float r2[64];
  __shared__ __align__(16) float scal[2];

  // ---- init: reduce X partials, c partials; load b_embed
  {
    float4 a = make_float4(0.f, 0.f, 0.f, 0.f);
    for (int ch = 0; ch < nch; ++ch) {
      const float4 p = *reinterpret_cast<const float4*>(
          Xp + (size_t)(b * nch + ch) * 4096 + t * 4);
      a.x += p.x; a.y += p.y; a.z += p.z; a.w += p.w;
    }
    *reinterpret_cast<float4*>(&Xs[0][0] + t * 4) = a;
    if (t < 64) {
      float s = 0.f;
      for (int ch = 0; ch < nch; ++ch) s += cp[(size_t)(b * nch + ch) * 64 + t];
      cvec[t] = s;
    }
    if (t < DM) bs[t] = bemb[t];
  }
  __syncthreads();

  float* u  = vec[0];
  float* s0 = vec[1];
  float* s1 = vec[2];
  float* A  = vec[3];
  float* Bv = vec[4];
  float* Dv = vec[5];

  const float* Wq0 = Wq;               const float* Wq1 = Wq + DM * DM;
  const float* Wk0 = Wk;               const float* Wk1 = Wk + DM * DM;
  const float* Wv0 = Wv;               const float* Wv1 = Wv + DM * DM;

  // u = c @ Wemb ; s0 = u + SEQ*b
  mv_NT<64>(Wemb, cvec, u, pm, t);
  if (t < DM) s0[t] = u[t] + (float)SEQ * bs[t];
  __syncthreads();

  // ---- layer 0: s1 = s0 + a*(((s0 Wq0) Wk0^T) G0) Wv0
  mv_NT<DM>(Wq0, s0, A, pm, t);                              // p
  mv_TN<DM>(Wk0, A, Bv, t);                                  // q = p @ Wk0^T
  apply_G0(Bv, A, Wemb, Xs, u, bs, r1, r2, pm, pms, scal, t);// r = q @ G0
  mv_NT<DM>(Wv0, A, Bv, pm, t);                              // w = r @ Wv0
  if (t < DM) s1[t] = s0[t] + RES_SCALE * Bv[t];
  __syncthreads();

  // ---- layer 1: s2 = s1 + a*((s1 Wq1 Wk1^T) G1) Wv1, G1 = A0^T G0 A0
  mv_NT<DM>(Wq1, s1, A, pm, t);                              // tv = s1 @ Wq1
  mv_TN<DM>(Wk1, A, Bv, t);                                  // t2 = tv @ Wk1^T (keep)
  // t2 @ A0^T = t2 + a*(((t2 Wv0^T) G0) Wk0) Wq0^T
  mv_TN<DM>(Wv0, Bv, A, t);                                  // y1
  apply_G0(A, Dv, Wemb, Xs, u, bs, r1, r2, pm, pms, scal, t);// y2
  mv_NT<DM>(Wk0, Dv, A, pm, t);                              // y3
  mv_TN<DM>(Wq0, A, Dv, t);                                  // y4
  if (t < DM) A[t] = Bv[t] + RES_SCALE * Dv[t];              // z = t2 @ A0^T
  __syncthreads();
  apply_G0(A, Bv, Wemb, Xs, u, bs, r1, r2, pm, pms, scal, t);// z2 = z @ G0
  // z3 = z2 @ A0 = z2 + a*(((z2 Wq0) Wk0^T) G0) Wv0
  mv_NT<DM>(Wq0, Bv, Dv, pm, t);                             // g1
  mv_TN<DM>(Wk0, Dv, A, t);                                  // g2
  apply_G0(A, Dv, Wemb, Xs, u, bs, r1, r2, pm, pms, scal, t);// g3
  mv_NT<DM>(Wv0, Dv, A, pm, t);                              // g4
  if (t < DM) Dv[t] = Bv[t] + RES_SCALE * A[t];              // z3
  __syncthreads();
  mv_NT<DM>(Wv1, Dv, A, pm, t);                              // w2 = z3 @ Wv1
  if (t < DM) Bv[t] = s1[t] + RES_SCALE * A[t];              // s2
  __syncthreads();

  // out[b] = dot(s2, Wout) + bout
  const int w = t >> 6, l = t & 63;
  if (w == 0) {
    const float4 a  = *reinterpret_cast<const float4*>(Bv + l * 4);
    const float4 ww = *reinterpret_cast<const float4*>(Wout + l * 4);
    float s = a.x * ww.x + a.y * ww.y + a.z * ww.z + a.w * ww.w;
    s = wave_red(s);
    if (l == 0) out[b] = s + bout[0];
  }
}

}  // namespace

extern "C" void kernel_launch(void* const* d_in, const int* in_sizes, int n_in,
                              void* d_out, int out_size, void* d_ws, size_t ws_size,
                              hipStream_t stream) {
  const float* x    = (const float*)d_in[0];
  const float* Wemb = (const float*)d_in[1];
  const float* bemb = (const float*)d_in[2];
  const float* Wq   = (const float*)d_in[3];
  const float* Wk   = (const float*)d_in[4];
  const float* Wv   = (const float*)d_in[5];
  const float* Wout = (const float*)d_in[6];
  const float* bout = (const float*)d_in[7];
  float* out = (float*)d_out;

  // pick chunk count that fits the workspace (preferred: 32 -> ~2.1 MB)
  int nch = 32;
  while (nch > 1 &&
         (size_t)(BATCH * nch) * (4096 + 64) * sizeof(float) > ws_size)
    nch >>= 1;

  float* Xp = (float*)d_ws;                       // [B*nch][64*64]
  float* cp = Xp + (size_t)BATCH * nch * 4096;    // [B*nch][64]

  k_xtx<<<BATCH * nch, 256, 0, stream>>>(x, Xp, cp, nch);
  k_chain<<<BATCH, 1024, 0, stream>>>(Xp, cp, Wemb, bemb, Wq, Wk, Wv,
                                      Wout, bout, out, nch);
}